// Round 5
// baseline (48.262 us; speedup 1.0000x reference)
//
#include <hip/hip_runtime.h>
#include <hip/hip_bf16.h>

#define NB 4
#define NT 2048
#define DM 1024
#define DH 64

typedef __attribute__((ext_vector_type(8))) short bf16x8;
typedef __attribute__((ext_vector_type(4))) float f32x4;
typedef unsigned short u16;
typedef unsigned int u32;

static __device__ __forceinline__ u16 f2b(float f) {
    __hip_bfloat16 h = __float2bfloat16(f);
    return __builtin_bit_cast(u16, h);
}
static __device__ __forceinline__ float b2f(u16 h) {
    return __builtin_bit_cast(float, (u32)h << 16);
}
// global -> LDS DMA, 16B per lane. lds ptr must be wave-uniform (HW adds lane*16).
static __device__ __forceinline__ void gld16(const void* g, void* l) {
    __builtin_amdgcn_global_load_lds((const __attribute__((address_space(1))) void*)g,
                                     (__attribute__((address_space(3))) void*)l, 16, 0, 0);
}
#define BAR() __builtin_amdgcn_s_barrier()
#define SBAR() __builtin_amdgcn_sched_barrier(0)

// ---------------------------------------------------------------------------
// Wt[which][d][k] bf16 <- W[k][d] fp32, via LDS transpose. grid (16, 3)
// ---------------------------------------------------------------------------
__global__ __launch_bounds__(256) void wt_conv(
    const float* __restrict__ WQ, const float* __restrict__ WK,
    const float* __restrict__ WV, u16* __restrict__ wt)
{
    __shared__ u16 tl[64][68];
    const int which = blockIdx.y, kt = blockIdx.x;
    const float* W = (which == 0) ? WQ : (which == 1) ? WK : WV;
    #pragma unroll
    for (int i = 0; i < 4; ++i) {
        int r = (threadIdx.x >> 4) + i * 16;         // k-local
        int c = (threadIdx.x & 15) * 4;              // d
        float4 v = *(const float4*)&W[(size_t)(kt * 64 + r) * DH + c];
        tl[r][c] = f2b(v.x); tl[r][c + 1] = f2b(v.y);
        tl[r][c + 2] = f2b(v.z); tl[r][c + 3] = f2b(v.w);
    }
    __syncthreads();
    int d = threadIdx.x >> 2, kc = (threadIdx.x & 3) * 16;
    u16 buf[16];
    #pragma unroll
    for (int j = 0; j < 16; ++j) buf[j] = tl[kc + j][d];
    u16* dst = wt + which * 65536 + d * 1024 + kt * 64 + kc;
    *(uint4*)dst = *(uint4*)&buf[0];
    *(uint4*)(dst + 8) = *(uint4*)&buf[8];
}

// ---------------------------------------------------------------------------
// QKV GEMM. grid (128, 3): 64-row tile x one of Q/K/V. 4 waves (16 rows each).
// Depth-2 pipeline, 3 LDS buffers, counted vmcnt (T3+T4): per stage each wave
// issues 6 gld16. At step kt: outstanding = stage(kt)+stage(kt+1)+stage(kt+2)
// = up to 18; wait vmcnt(12) retires stage(kt). Tail: kt=14 -> vmcnt(6),
// kt=15 -> vmcnt(0). Raw s_barrier (no vmcnt(0) drain).
// ---------------------------------------------------------------------------
__global__ __launch_bounds__(256) void qkv_gemm(
    const float* __restrict__ x, const u16* __restrict__ wt,
    u16* __restrict__ Qb, u16* __restrict__ Kb, u16* __restrict__ Vt)
{
    __shared__ float xs[3][4096];     // 3 x 16 KB fp32, swizzle ^((r&7)<<5)
    __shared__ u16 wsm[3][4096];      // 3 x  8 KB bf16, swizzle ^((r&7)<<4)
    const int tid = threadIdx.x, lane = tid & 63, w = tid >> 6;
    const int l15 = lane & 15, g = lane >> 4;
    const int row0 = blockIdx.x * 64;
    const int which = blockIdx.y;
    const u16* Wg = wt + which * 65536;

    auto stage = [&](int kt, int bi) {
        #pragma unroll
        for (int i = 0; i < 4; ++i) {
            u32 D = (u32)(w * 4096 + i * 1024 + lane * 16);
            u32 r = D >> 8, c = D & 255;
            u32 cs = c ^ ((r & 7) << 5);
            gld16(x + (size_t)(row0 + r) * DM + kt * 64 + (cs >> 2),
                  (char*)&xs[bi][0] + w * 4096 + i * 1024);
        }
        #pragma unroll
        for (int i = 0; i < 2; ++i) {
            u32 D = (u32)(w * 2048 + i * 1024 + lane * 16);
            u32 r = D >> 7, c = D & 127;
            u32 cs = c ^ ((r & 7) << 4);
            gld16(Wg + (size_t)r * 1024 + kt * 64 + (cs >> 1),
                  (char*)&wsm[bi][0] + w * 2048 + i * 1024);
        }
    };

    f32x4 acc[4];
    #pragma unroll
    for (int i = 0; i < 4; ++i) acc[i] = {0.f, 0.f, 0.f, 0.f};

    stage(0, 0);
    stage(1, 1);

    const int arow = w * 16 + l15;
    #pragma unroll
    for (int kt = 0; kt < 16; ++kt) {
        if (kt + 2 < 16) stage(kt + 2, (kt + 2) % 3);
        if (kt < 14)       asm volatile("s_waitcnt vmcnt(12)" ::: "memory");
        else if (kt == 14) asm volatile("s_waitcnt vmcnt(6)" ::: "memory");
        else               asm volatile("s_waitcnt vmcnt(0)" ::: "memory");
        BAR();                                    // publish buf[kt%3]
        SBAR();
        const char* xb = (const char*)&xs[kt % 3][0];
        const char* wb = (const char*)&wsm[kt % 3][0];
        #pragma unroll
        for (int ks = 0; ks < 2; ++ks) {
            u32 abase = (u32)(arow * 256 + ks * 128 + g * 32);
            f32x4 a0 = *(const f32x4*)(xb + (abase ^ ((arow & 7) << 5)));
            f32x4 a1 = *(const f32x4*)(xb + ((abase + 16) ^ ((arow & 7) << 5)));
            bf16x8 afrag;
            #pragma unroll
            for (int e = 0; e < 4; ++e) afrag[e] = (short)f2b(a0[e]);
            #pragma unroll
            for (int e = 0; e < 4; ++e) afrag[4 + e] = (short)f2b(a1[e]);
            __builtin_amdgcn_s_setprio(1);
            #pragma unroll
            for (int nt = 0; nt < 4; ++nt) {
                int brow = nt * 16 + l15;
                u32 bb = (u32)(brow * 128 + ks * 64 + g * 16);
                bf16x8 bfrag = *(const bf16x8*)(wb + (bb ^ ((brow & 7) << 4)));
                acc[nt] = __builtin_amdgcn_mfma_f32_16x16x32_bf16(afrag, bfrag, acc[nt], 0, 0, 0);
            }
            __builtin_amdgcn_s_setprio(0);
        }
        BAR();                                    // release buf[kt%3]
    }
    // epilogue: C col=l15(+16nt), row=g*4+r
    #pragma unroll
    for (int nt = 0; nt < 4; ++nt) {
        int dcol = nt * 16 + l15;
        #pragma unroll
        for (int r = 0; r < 4; ++r) {
            int row = row0 + w * 16 + g * 4 + r;
            float v = acc[nt][r];
            if (which == 0)      Qb[(size_t)row * DH + dcol] = f2b(v * 0.125f);
            else if (which == 1) Kb[(size_t)row * DH + dcol] = f2b(v);
            else { int bb2 = row >> 11, t = row & 2047;
                   Vt[(size_t)bb2 * DH * NT + (size_t)dcol * NT + t] = f2b(v); }
        }
    }
}

// ---------------------------------------------------------------------------
// Flash attention, double-buffered K/V with counted vmcnt (4 gld16/stage/wave:
// wait vmcnt(4) when next stage in flight, vmcnt(0) on last tile). Block =
// 4 waves x 16 q-rows (QBLK=64). Balanced KV chunking; partials merged.
// ---------------------------------------------------------------------------
__global__ __launch_bounds__(256) void attn(
    const u16* __restrict__ Qb, const u16* __restrict__ Kb,
    const u16* __restrict__ Vt, u16* __restrict__ pO, float* __restrict__ pml,
    int CHUNK, int SLOTS)
{
    __shared__ u16 k_lds[2][4096];
    __shared__ u16 v_lds[2][4096];
    __shared__ u16 p_lds[4][16 * 72];

    const int tid = threadIdx.x, lane = tid & 63, w = tid >> 6;
    const int l15 = lane & 15, g = lane >> 4;
    const int b = blockIdx.y;

    // decode blockIdx.x -> (qb, chunk)
    int flat = blockIdx.x, qb = 0, nc;
    for (;;) { nc = (qb + CHUNK) / CHUNK; if (flat < nc) break; flat -= nc; ++qb; }
    const int chunk = flat;
    const int t0 = chunk * CHUNK;
    const int t1 = min(t0 + CHUNK, qb + 1);
    const int q0 = qb * 64;

    const u16* Qg = Qb + ((size_t)b * NT + q0 + w * 16) * DH;
    const u16* Kg = Kb + (size_t)b * NT * DH;
    const u16* Vg = Vt + (size_t)b * DH * NT;

    auto stage = [&](int t, int bi) {
        const int j0 = t * 64;
        #pragma unroll
        for (int i = 0; i < 2; ++i) {
            u32 D = (u32)(w * 2048 + i * 1024 + lane * 16);
            u32 r = D >> 7, c = D & 127;
            u32 cs = c ^ ((r & 7) << 4);
            gld16(Kg + (size_t)(j0 + r) * DH + (cs >> 1),
                  (char*)&k_lds[bi][0] + w * 2048 + i * 1024);
            gld16(Vg + (size_t)r * NT + j0 + (cs >> 1),
                  (char*)&v_lds[bi][0] + w * 2048 + i * 1024);
        }
    };

    stage(t0, 0);

    bf16x8 qf[2];
    qf[0] = *(const bf16x8*)(Qg + l15 * DH + g * 8);
    qf[1] = *(const bf16x8*)(Qg + l15 * DH + 32 + g * 8);

    float m_run[4], l_run[4];
    f32x4 oacc[4];
    #pragma unroll
    for (int r = 0; r < 4; ++r) { m_run[r] = -INFINITY; l_run[r] = 0.f; }
    #pragma unroll
    for (int nt = 0; nt < 4; ++nt) oacc[nt] = {0.f, 0.f, 0.f, 0.f};

    for (int t = t0; t < t1; ++t) {
        const int cur = (t - t0) & 1;
        if (t + 1 < t1) {
            stage(t + 1, cur ^ 1);                // in flight across compute
            asm volatile("s_waitcnt vmcnt(4)" ::: "memory");  // cur's 4 landed
        } else {
            asm volatile("s_waitcnt vmcnt(0)" ::: "memory");
        }
        BAR();                                    // publish cur
        SBAR();
        const char* kb = (const char*)&k_lds[cur][0];
        const char* vb = (const char*)&v_lds[cur][0];

        // ---- QK^T ----
        f32x4 sacc[4];
        #pragma unroll
        for (int nt = 0; nt < 4; ++nt) sacc[nt] = {0.f, 0.f, 0.f, 0.f};
        __builtin_amdgcn_s_setprio(1);
        #pragma unroll
        for (int ks = 0; ks < 2; ++ks) {
            #pragma unroll
            for (int nt = 0; nt < 4; ++nt) {
                int brow = nt * 16 + l15;
                u32 bb = (u32)(brow * 128 + ks * 64 + g * 16);
                bf16x8 bf = *(const bf16x8*)(kb + (bb ^ ((brow & 7) << 4)));
                sacc[nt] = __builtin_amdgcn_mfma_f32_16x16x32_bf16(qf[ks], bf, sacc[nt], 0, 0, 0);
            }
        }
        __builtin_amdgcn_s_setprio(0);
        if (t == qb) {  // causal mask, diagonal tile only
            #pragma unroll
            for (int nt = 0; nt < 4; ++nt) {
                int j_local = nt * 16 + l15;
                #pragma unroll
                for (int r = 0; r < 4; ++r) {
                    int q_local = w * 16 + g * 4 + r;
                    if (j_local > q_local) sacc[nt][r] = -1e30f;
                }
            }
        }
        // ---- online softmax ----
        float p[4][4];
        #pragma unroll
        for (int r = 0; r < 4; ++r) {
            float mx = fmaxf(fmaxf(sacc[0][r], sacc[1][r]), fmaxf(sacc[2][r], sacc[3][r]));
            mx = fmaxf(mx, __shfl_xor(mx, 1));
            mx = fmaxf(mx, __shfl_xor(mx, 2));
            mx = fmaxf(mx, __shfl_xor(mx, 4));
            mx = fmaxf(mx, __shfl_xor(mx, 8));
            float m_new = fmaxf(m_run[r], mx);
            float alpha = __expf(m_run[r] - m_new);
            float ps = 0.f;
            #pragma unroll
            for (int nt = 0; nt < 4; ++nt) {
                float pv = __expf(sacc[nt][r] - m_new);
                p[nt][r] = pv; ps += pv;
            }
            ps += __shfl_xor(ps, 1); ps += __shfl_xor(ps, 2);
            ps += __shfl_xor(ps, 4); ps += __shfl_xor(ps, 8);
            l_run[r] = l_run[r] * alpha + ps;
            m_run[r] = m_new;
            #pragma unroll
            for (int nt = 0; nt < 4; ++nt) oacc[nt][r] *= alpha;
        }
        // ---- P -> per-wave LDS (stride 72), re-read in A layout ----
        u16* pw = p_lds[w];
        #pragma unroll
        for (int r = 0; r < 4; ++r) {
            int qrow = g * 4 + r;
            #pragma unroll
            for (int nt = 0; nt < 4; ++nt)
                pw[qrow * 72 + nt * 16 + l15] = f2b(p[nt][r]);
        }
        // ---- PV ----
        __builtin_amdgcn_s_setprio(1);
        #pragma unroll
        for (int ks = 0; ks < 2; ++ks) {
            bf16x8 pa = *(const bf16x8*)((const char*)pw + (l15 * 144 + ks * 64 + g * 16));
            #pragma unroll
            for (int nt = 0; nt < 4; ++nt) {
                int drow = nt * 16 + l15;
                u32 bb = (u32)(drow * 128 + ks * 64 + g * 16);
                bf16x8 vf = *(const bf16x8*)(vb + (bb ^ ((drow & 7) << 4)));
                oacc[nt] = __builtin_amdgcn_mfma_f32_16x16x32_bf16(pa, vf, oacc[nt], 0, 0, 0);
            }
        }
        __builtin_amdgcn_s_setprio(0);
        BAR();                                    // release cur
    }

    const int slot = (b * 32 + qb) * SLOTS + chunk;
    u16* Op = pO + (size_t)slot * 4096;
    #pragma unroll
    for (int nt = 0; nt < 4; ++nt)
        #pragma unroll
        for (int r = 0; r < 4; ++r)
            Op[(w * 16 + g * 4 + r) * 64 + nt * 16 + l15] = f2b(oacc[nt][r]);
    if (l15 == 0) {
        float* mlp = pml + (size_t)slot * 128;
        #pragma unroll
        for (int r = 0; r < 4; ++r) {
            int row = w * 16 + g * 4 + r;
            mlp[row * 2]     = m_run[r];
            mlp[row * 2 + 1] = l_run[r];
        }
    }
}

// ---------------------------------------------------------------------------
// Merge <=SLOTS partials per q-row; fp32 output.
// ---------------------------------------------------------------------------
__global__ __launch_bounds__(256) void merge(
    const u16* __restrict__ pO, const float* __restrict__ pml,
    float* __restrict__ out, int CHUNK, int SLOTS)
{
    int idx = blockIdx.x * 256 + threadIdx.x;
    int row = idx >> 6, d = idx & 63;
    int b = row >> 11, q = row & 2047;
    int qb = q >> 6, rl = q & 63;
    int nc = (qb + CHUNK) / CHUNK;
    int base = (b * 32 + qb) * SLOTS;
    float m = -INFINITY;
    for (int c = 0; c < nc; ++c)
        m = fmaxf(m, pml[(size_t)(base + c) * 128 + rl * 2]);
    float osum = 0.f, lsum = 0.f;
    for (int c = 0; c < nc; ++c) {
        float mc = pml[(size_t)(base + c) * 128 + rl * 2];
        float lc = pml[(size_t)(base + c) * 128 + rl * 2 + 1];
        float wgt = __expf(mc - m);
        osum += wgt * b2f(pO[(size_t)(base + c) * 4096 + rl * 64 + d]);
        lsum += wgt * lc;
    }
    out[idx] = osum / lsum;
}

extern "C" void kernel_launch(void* const* d_in, const int* in_sizes, int n_in,
                              void* d_out, int out_size, void* d_ws, size_t ws_size,
                              hipStream_t stream) {
    const float* x  = (const float*)d_in[0];
    const float* WQ = (const float*)d_in[1];
    const float* WK = (const float*)d_in[2];
    const float* WV = (const float*)d_in[3];
    float* out = (float*)d_out;

    char* ws = (char*)d_ws;
    u16* Qb = (u16*)ws;                       // 1 MB
    u16* Kb = (u16*)(ws + 1048576);           // 1 MB
    u16* Vt = (u16*)(ws + 2097152);           // 1 MB
    u16* Wt = (u16*)(ws + 3145728);           // 384 KB (dead after qkv_gemm)
    // partials overlap Wt (attn runs after qkv_gemm on the same stream)
    int CHUNK, SLOTS;
    if (ws_size >= 9830400) { CHUNK = 6;  SLOTS = 6; }   // 408 blocks, max 6 tiles
    else                    { CHUNK = 16; SLOTS = 2; }
    u16*   pO  = (u16*)(ws + 3145728);
    float* pml = (float*)(ws + 3145728 + (size_t)NB * 32 * SLOTS * 4096 * 2);

    int gx = 0;
    for (int qb = 0; qb < 32; ++qb) gx += (qb + CHUNK) / CHUNK;  // 102 or 48

    wt_conv<<<dim3(16, 3), 256, 0, stream>>>(WQ, WK, WV, Wt);
    qkv_gemm<<<dim3(128, 3), 256, 0, stream>>>(x, Wt, Qb, Kb, Vt);
    attn<<<dim3(gx, NB), 256, 0, stream>>>(Qb, Kb, Vt, pO, pml, CHUNK, SLOTS);
    merge<<<2048, 256, 0, stream>>>(pO, pml, out, CHUNK, SLOTS);
}

// Round 6
// 45.624 us; speedup vs baseline: 1.0578x; 1.0578x over previous
//
#include <hip/hip_runtime.h>
#include <hip/hip_bf16.h>

#define NB 4
#define NT 2048
#define DM 1024
#define DH 64

typedef __attribute__((ext_vector_type(8))) short bf16x8;
typedef __attribute__((ext_vector_type(4))) float f32x4;
typedef unsigned short u16;
typedef unsigned int u32;

static __device__ __forceinline__ u16 f2b(float f) {
    __hip_bfloat16 h = __float2bfloat16(f);
    return __builtin_bit_cast(u16, h);
}
static __device__ __forceinline__ float b2f(u16 h) {
    return __builtin_bit_cast(float, (u32)h << 16);
}
// global -> LDS DMA, 16B per lane. lds ptr must be wave-uniform (HW adds lane*16).
static __device__ __forceinline__ void gld16(const void* g, void* l) {
    __builtin_amdgcn_global_load_lds((const __attribute__((address_space(1))) void*)g,
                                     (__attribute__((address_space(3))) void*)l, 16, 0, 0);
}
#define BAR() __builtin_amdgcn_s_barrier()
#define SBAR() __builtin_amdgcn_sched_barrier(0)

// ---------------------------------------------------------------------------
// Wt[which][d][k] bf16 <- W[k][d] fp32, via LDS transpose. grid (16, 3)
// ---------------------------------------------------------------------------
__global__ __launch_bounds__(256) void wt_conv(
    const float* __restrict__ WQ, const float* __restrict__ WK,
    const float* __restrict__ WV, u16* __restrict__ wt)
{
    __shared__ u16 tl[64][68];
    const int which = blockIdx.y, kt = blockIdx.x;
    const float* W = (which == 0) ? WQ : (which == 1) ? WK : WV;
    #pragma unroll
    for (int i = 0; i < 4; ++i) {
        int r = (threadIdx.x >> 4) + i * 16;         // k-local
        int c = (threadIdx.x & 15) * 4;              // d
        float4 v = *(const float4*)&W[(size_t)(kt * 64 + r) * DH + c];
        tl[r][c] = f2b(v.x); tl[r][c + 1] = f2b(v.y);
        tl[r][c + 2] = f2b(v.z); tl[r][c + 3] = f2b(v.w);
    }
    __syncthreads();
    int d = threadIdx.x >> 2, kc = (threadIdx.x & 3) * 16;
    u16 buf[16];
    #pragma unroll
    for (int j = 0; j < 16; ++j) buf[j] = tl[kc + j][d];
    u16* dst = wt + which * 65536 + d * 1024 + kt * 64 + kc;
    *(uint4*)dst = *(uint4*)&buf[0];
    *(uint4*)(dst + 8) = *(uint4*)&buf[8];
}

// ---------------------------------------------------------------------------
// QKV GEMM. grid (128, 3): 64-row tile x one of Q/K/V. 4 waves (16 rows each).
// 2-buffer pipeline, counted vmcnt (6 DMA/wave/stage): at step kt, outstanding
// = stage(kt)+stage(kt+1) = 12; vmcnt(6) retires stage(kt). Last step vmcnt(0).
// ---------------------------------------------------------------------------
__global__ __launch_bounds__(256) void qkv_gemm(
    const float* __restrict__ x, const u16* __restrict__ wt,
    u16* __restrict__ Qb, u16* __restrict__ Kb, u16* __restrict__ Vt)
{
    __shared__ float xs[2][4096];     // 2 x 16 KB fp32, swizzle ^((r&7)<<5)
    __shared__ u16 wsm[2][4096];      // 2 x  8 KB bf16, swizzle ^((r&7)<<4)
    const int tid = threadIdx.x, lane = tid & 63, w = tid >> 6;
    const int l15 = lane & 15, g = lane >> 4;
    const int row0 = blockIdx.x * 64;
    const int which = blockIdx.y;
    const u16* Wg = wt + which * 65536;

    auto stage = [&](int kt, int bi) {
        #pragma unroll
        for (int i = 0; i < 4; ++i) {
            u32 D = (u32)(w * 4096 + i * 1024 + lane * 16);
            u32 r = D >> 8, c = D & 255;
            u32 cs = c ^ ((r & 7) << 5);
            gld16(x + (size_t)(row0 + r) * DM + kt * 64 + (cs >> 2),
                  (char*)&xs[bi][0] + w * 4096 + i * 1024);
        }
        #pragma unroll
        for (int i = 0; i < 2; ++i) {
            u32 D = (u32)(w * 2048 + i * 1024 + lane * 16);
            u32 r = D >> 7, c = D & 127;
            u32 cs = c ^ ((r & 7) << 4);
            gld16(Wg + (size_t)r * 1024 + kt * 64 + (cs >> 1),
                  (char*)&wsm[bi][0] + w * 2048 + i * 1024);
        }
    };

    f32x4 acc[4];
    #pragma unroll
    for (int i = 0; i < 4; ++i) acc[i] = {0.f, 0.f, 0.f, 0.f};

    stage(0, 0);

    const int arow = w * 16 + l15;
    #pragma unroll
    for (int kt = 0; kt < 16; ++kt) {
        if (kt < 15) {
            stage(kt + 1, (kt + 1) & 1);
            asm volatile("s_waitcnt vmcnt(6)" ::: "memory");
        } else {
            asm volatile("s_waitcnt vmcnt(0)" ::: "memory");
        }
        BAR();                                    // publish buf[kt&1]
        SBAR();
        const char* xb = (const char*)&xs[kt & 1][0];
        const char* wb = (const char*)&wsm[kt & 1][0];
        #pragma unroll
        for (int ks = 0; ks < 2; ++ks) {
            u32 abase = (u32)(arow * 256 + ks * 128 + g * 32);
            f32x4 a0 = *(const f32x4*)(xb + (abase ^ ((arow & 7) << 5)));
            f32x4 a1 = *(const f32x4*)(xb + ((abase + 16) ^ ((arow & 7) << 5)));
            bf16x8 afrag;
            #pragma unroll
            for (int e = 0; e < 4; ++e) afrag[e] = (short)f2b(a0[e]);
            #pragma unroll
            for (int e = 0; e < 4; ++e) afrag[4 + e] = (short)f2b(a1[e]);
            __builtin_amdgcn_s_setprio(1);
            #pragma unroll
            for (int nt = 0; nt < 4; ++nt) {
                int brow = nt * 16 + l15;
                u32 bb = (u32)(brow * 128 + ks * 64 + g * 16);
                bf16x8 bfrag = *(const bf16x8*)(wb + (bb ^ ((brow & 7) << 4)));
                acc[nt] = __builtin_amdgcn_mfma_f32_16x16x32_bf16(afrag, bfrag, acc[nt], 0, 0, 0);
            }
            __builtin_amdgcn_s_setprio(0);
        }
        BAR();                                    // release buf[kt&1]
    }
    // epilogue: C col=l15(+16nt), row=g*4+r
    #pragma unroll
    for (int nt = 0; nt < 4; ++nt) {
        int dcol = nt * 16 + l15;
        #pragma unroll
        for (int r = 0; r < 4; ++r) {
            int row = row0 + w * 16 + g * 4 + r;
            float v = acc[nt][r];
            if (which == 0)      Qb[(size_t)row * DH + dcol] = f2b(v * 0.125f);
            else if (which == 1) Kb[(size_t)row * DH + dcol] = f2b(v);
            else { int bb2 = row >> 11, t = row & 2047;
                   Vt[(size_t)bb2 * DH * NT + (size_t)dcol * NT + t] = f2b(v); }
        }
    }
}

// ---------------------------------------------------------------------------
// Flash attention, SWAPPED operands (T12 idea): St = mfma(K, Q) -> C col=q,
// row=j. Each lane owns one q-row's scores (16 of 64 j in-register) =>
// softmax is in-register + 2 shfl_xor. PV = mfma(Vt, P^T) -> O^T, stored
// transposed to pOt [d][q]. 4 waves x 16 q (QBLK=64), KVBLK=64, 2-buf DMA
// with counted vmcnt. Balanced KV chunking; partials merged by merge().
// ---------------------------------------------------------------------------
__global__ __launch_bounds__(256) void attn(
    const u16* __restrict__ Qb, const u16* __restrict__ Kb,
    const u16* __restrict__ Vt, u16* __restrict__ pOt, float* __restrict__ pml,
    int CHUNK, int SLOTS)
{
    __shared__ u16 k_lds[2][4096];
    __shared__ u16 v_lds[2][4096];
    __shared__ f32x4 p_lds[4][128];   // per-wave P rows, [q=16][j=64] bf16 swz

    const int tid = threadIdx.x, lane = tid & 63, w = tid >> 6;
    const int l15 = lane & 15, g = lane >> 4;
    const int b = blockIdx.y;

    // decode blockIdx.x -> (qb, chunk)
    int flat = blockIdx.x, qb = 0, nc;
    for (;;) { nc = (qb + CHUNK) / CHUNK; if (flat < nc) break; flat -= nc; ++qb; }
    const int chunk = flat;
    const int t0 = chunk * CHUNK;
    const int t1 = min(t0 + CHUNK, qb + 1);
    const int q0 = qb * 64;

    const u16* Qg = Qb + ((size_t)b * NT + q0 + w * 16) * DH;
    const u16* Kg = Kb + (size_t)b * NT * DH;
    const u16* Vg = Vt + (size_t)b * DH * NT;

    auto stage = [&](int t, int bi) {
        const int j0 = t * 64;
        #pragma unroll
        for (int i = 0; i < 2; ++i) {
            u32 D = (u32)(w * 2048 + i * 1024 + lane * 16);
            u32 r = D >> 7, c = D & 127;
            u32 cs = c ^ ((r & 7) << 4);
            gld16(Kg + (size_t)(j0 + r) * DH + (cs >> 1),
                  (char*)&k_lds[bi][0] + w * 2048 + i * 1024);
            gld16(Vg + (size_t)r * NT + j0 + (cs >> 1),
                  (char*)&v_lds[bi][0] + w * 2048 + i * 1024);
        }
    };

    stage(t0, 0);

    // Q fragment, B-operand: col=l15 -> q = w*16+l15, k = ks*32+g*8+e over d
    bf16x8 qf[2];
    qf[0] = *(const bf16x8*)(Qg + l15 * DH + g * 8);
    qf[1] = *(const bf16x8*)(Qg + l15 * DH + 32 + g * 8);

    float m_run = -INFINITY, l_run = 0.f;
    f32x4 oacc[4];                    // O^T: d = nt*16+g*4+r, q = w*16+l15
    #pragma unroll
    for (int nt = 0; nt < 4; ++nt) oacc[nt] = {0.f, 0.f, 0.f, 0.f};

    char* pw = (char*)&p_lds[w][0];
    const int swz = (l15 & 7) << 4;

    for (int t = t0; t < t1; ++t) {
        const int cur = (t - t0) & 1;
        if (t + 1 < t1) {
            stage(t + 1, cur ^ 1);
            asm volatile("s_waitcnt vmcnt(4)" ::: "memory");
        } else {
            asm volatile("s_waitcnt vmcnt(0)" ::: "memory");
        }
        BAR();                                    // publish cur
        SBAR();
        const char* kb = (const char*)&k_lds[cur][0];
        const char* vb = (const char*)&v_lds[cur][0];

        // ---- QK^T swapped: sacc[nt][r] = S[j = nt*16+g*4+r][q = w*16+l15]
        f32x4 sacc[4];
        #pragma unroll
        for (int nt = 0; nt < 4; ++nt) sacc[nt] = {0.f, 0.f, 0.f, 0.f};
        __builtin_amdgcn_s_setprio(1);
        #pragma unroll
        for (int ks = 0; ks < 2; ++ks) {
            #pragma unroll
            for (int nt = 0; nt < 4; ++nt) {
                int arow = nt * 16 + l15;          // j
                u32 aa = (u32)(arow * 128 + ks * 64 + g * 16);
                bf16x8 kf = *(const bf16x8*)(kb + (aa ^ ((arow & 7) << 4)));
                sacc[nt] = __builtin_amdgcn_mfma_f32_16x16x32_bf16(kf, qf[ks], sacc[nt], 0, 0, 0);
            }
        }
        __builtin_amdgcn_s_setprio(0);
        if (t == qb) {  // causal mask, diagonal tile only
            const int q_local = w * 16 + l15;
            #pragma unroll
            for (int nt = 0; nt < 4; ++nt)
                #pragma unroll
                for (int r = 0; r < 4; ++r)
                    if (nt * 16 + g * 4 + r > q_local) sacc[nt][r] = -1e30f;
        }
        // ---- online softmax: per-lane over 16 values + xor16/xor32 ----
        float mx = -INFINITY;
        #pragma unroll
        for (int nt = 0; nt < 4; ++nt) {
            float a = fmaxf(fmaxf(sacc[nt][0], sacc[nt][1]),
                            fmaxf(sacc[nt][2], sacc[nt][3]));
            mx = fmaxf(mx, a);
        }
        mx = fmaxf(mx, __shfl_xor(mx, 16));
        mx = fmaxf(mx, __shfl_xor(mx, 32));
        const float m_new = fmaxf(m_run, mx);
        const float alpha = __expf(m_run - m_new);
        float p[4][4];
        float ps = 0.f;
        #pragma unroll
        for (int nt = 0; nt < 4; ++nt)
            #pragma unroll
            for (int r = 0; r < 4; ++r) {
                float pv = __expf(sacc[nt][r] - m_new);
                p[nt][r] = pv; ps += pv;
            }
        ps += __shfl_xor(ps, 16);
        ps += __shfl_xor(ps, 32);
        l_run = l_run * alpha + ps;
        m_run = m_new;
        #pragma unroll
        for (int nt = 0; nt < 4; ++nt)
            #pragma unroll
            for (int r = 0; r < 4; ++r) oacc[nt][r] *= alpha;

        // ---- P^T repack via tiny per-wave LDS: row q=l15, byte j*2, swz ----
        #pragma unroll
        for (int nt = 0; nt < 4; ++nt) {
            uint2 pk;
            pk.x = (u32)f2b(p[nt][0]) | ((u32)f2b(p[nt][1]) << 16);
            pk.y = (u32)f2b(p[nt][2]) | ((u32)f2b(p[nt][3]) << 16);
            u32 a = (u32)((l15 * 128 + nt * 32 + g * 8) ^ swz);
            *(uint2*)(pw + a) = pk;
        }
        bf16x8 pb[2];
        #pragma unroll
        for (int ks = 0; ks < 2; ++ks)
            pb[ks] = *(const bf16x8*)(pw + ((u32)(l15 * 128 + ks * 64 + g * 16) ^ swz));

        // ---- PV swapped: oacc[nt] += Vt[d][j] @ P^T[j][q] ----
        __builtin_amdgcn_s_setprio(1);
        #pragma unroll
        for (int ks = 0; ks < 2; ++ks) {
            #pragma unroll
            for (int nt = 0; nt < 4; ++nt) {
                int arow = nt * 16 + l15;          // d
                u32 aa = (u32)(arow * 128 + ks * 64 + g * 16);
                bf16x8 vf = *(const bf16x8*)(vb + (aa ^ ((arow & 7) << 4)));
                oacc[nt] = __builtin_amdgcn_mfma_f32_16x16x32_bf16(vf, pb[ks], oacc[nt], 0, 0, 0);
            }
        }
        __builtin_amdgcn_s_setprio(0);
        BAR();                                    // release cur
    }

    // write partials: O^T [d][q] bf16 (coalesced in l15), m/l per q
    const int slot = (b * 32 + qb) * SLOTS + chunk;
    u16* Op = pOt + (size_t)slot * 4096;
    #pragma unroll
    for (int nt = 0; nt < 4; ++nt)
        #pragma unroll
        for (int r = 0; r < 4; ++r)
            Op[(nt * 16 + g * 4 + r) * 64 + w * 16 + l15] = f2b(oacc[nt][r]);
    if (g == 0) {
        float* mlp = pml + (size_t)slot * 128;
        mlp[(w * 16 + l15) * 2]     = m_run;
        mlp[(w * 16 + l15) * 2 + 1] = l_run;
    }
}

// ---------------------------------------------------------------------------
// Merge <=SLOTS transposed partials per (b,qb); LDS transpose; fp32 out [q][d].
// grid = NB*32 blocks.
// ---------------------------------------------------------------------------
__global__ __launch_bounds__(256) void merge(
    const u16* __restrict__ pOt, const float* __restrict__ pml,
    float* __restrict__ out, int CHUNK, int SLOTS)
{
    __shared__ float tl[64][65];
    const int bq = blockIdx.x;             // b*32 + qb
    const int b = bq >> 5, qb = bq & 31;
    const int nc = (qb + CHUNK) / CHUNK;
    const int base = bq * SLOTS;
    const int q = threadIdx.x & 63, ds = threadIdx.x >> 6;

    float m = -INFINITY;
    for (int c = 0; c < nc; ++c)
        m = fmaxf(m, pml[(size_t)(base + c) * 128 + q * 2]);
    float lsum = 0.f;
    float acc[16];
    #pragma unroll
    for (int i = 0; i < 16; ++i) acc[i] = 0.f;
    for (int c = 0; c < nc; ++c) {
        const float mc = pml[(size_t)(base + c) * 128 + q * 2];
        const float lc = pml[(size_t)(base + c) * 128 + q * 2 + 1];
        const float wc = __expf(mc - m);
        lsum += wc * lc;
        const u16* Op = pOt + (size_t)(base + c) * 4096;
        #pragma unroll
        for (int i = 0; i < 16; ++i)
            acc[i] += wc * b2f(Op[(ds * 16 + i) * 64 + q]);
    }
    const float inv = 1.f / lsum;
    #pragma unroll
    for (int i = 0; i < 16; ++i) tl[q][ds * 16 + i] = acc[i] * inv;
    __syncthreads();
    const int q2 = threadIdx.x >> 2, dc = threadIdx.x & 3;
    float* orow = out + ((size_t)b * NT + qb * 64 + q2) * 64 + dc * 16;
    #pragma unroll
    for (int j4 = 0; j4 < 4; ++j4) {
        float4 v = { tl[q2][dc * 16 + j4 * 4 + 0], tl[q2][dc * 16 + j4 * 4 + 1],
                     tl[q2][dc * 16 + j4 * 4 + 2], tl[q2][dc * 16 + j4 * 4 + 3] };
        *(float4*)&orow[j4 * 4] = v;
    }
}

extern "C" void kernel_launch(void* const* d_in, const int* in_sizes, int n_in,
                              void* d_out, int out_size, void* d_ws, size_t ws_size,
                              hipStream_t stream) {
    const float* x  = (const float*)d_in[0];
    const float* WQ = (const float*)d_in[1];
    const float* WK = (const float*)d_in[2];
    const float* WV = (const float*)d_in[3];
    float* out = (float*)d_out;

    char* ws = (char*)d_ws;
    u16* Qb = (u16*)ws;                       // 1 MB
    u16* Kb = (u16*)(ws + 1048576);           // 1 MB
    u16* Vt = (u16*)(ws + 2097152);           // 1 MB
    u16* Wt = (u16*)(ws + 3145728);           // 384 KB (dead after qkv_gemm)
    // partials overlap Wt (attn runs after qkv_gemm on the same stream)
    int CHUNK, SLOTS;
    if (ws_size >= 9830400) { CHUNK = 6;  SLOTS = 6; }   // 408 blocks, max 6 tiles
    else                    { CHUNK = 16; SLOTS = 2; }
    u16*   pOt = (u16*)(ws + 3145728);
    float* pml = (float*)(ws + 3145728 + (size_t)NB * 32 * SLOTS * 4096 * 2);

    int gx = 0;
    for (int qb = 0; qb < 32; ++qb) gx += (qb + CHUNK) / CHUNK;  // 102 or 48

    wt_conv<<<dim3(16, 3), 256, 0, stream>>>(WQ, WK, WV, Wt);
    qkv_gemm<<<dim3(128, 3), 256, 0, stream>>>(x, Wt, Qb, Kb, Vt);
    attn<<<dim3(gx, NB), 256, 0, stream>>>(Qb, Kb, Vt, pOt, pml, CHUNK, SLOTS);
    merge<<<NB * 32, 256, 0, stream>>>(pOt, pml, out, CHUNK, SLOTS);
}